// Round 6
// baseline (51.100 us; speedup 1.0000x reference)
//
#include <hip/hip_runtime.h>
#include <hip/hip_bf16.h>
#include <stdint.h>

// Problem constants (from reference)
#define N_SAMP 16384
#define DCONT  64
#define DCAT   2000
#define EMB    64
#define K_CAT_PAD 2048          // 64 bit-words per row (2048 bits, 2000..2047 zero)
#define K_PAD     2112          // + 64 continuous K at the end of B
#define BM 32                   // rows per block in fm_kernel
#define BM_OFF 270336           // byte offset of bitmask in d_ws (64*2112*2 bytes of B first)

typedef short bf16x8 __attribute__((ext_vector_type(8)));
typedef float f32x4  __attribute__((ext_vector_type(4)));

__device__ __forceinline__ uint16_t f2bf(float f) {
    union { float f; uint32_t u; } v; v.f = f;
    uint32_t r = v.u + 0x7FFFu + ((v.u >> 16) & 1u);   // RNE
    return (uint16_t)(r >> 16);
}
__device__ __forceinline__ uint32_t pack2f(float a, float b) {
    return (uint32_t)f2bf(a) | ((uint32_t)f2bf(b) << 16);
}

// Build B_T[c][k] (bf16), c in [0,64), k in [0,2112):
//   k <  2000          : W_cat[k][c]
//   2000 <= k < 2048   : 0
//   2048 <= k < 2112   : W_cont[k-2048][c]
__global__ void build_b_kernel(const float* __restrict__ Wcont,
                               const float* __restrict__ Wcat,
                               uint16_t* __restrict__ Bws) {
    int k = blockIdx.x * 64 + threadIdx.x;   // coalesced along k
    int c = blockIdx.y;
    float v = 0.f;
    if (k < DCAT)            v = Wcat[(long)k * EMB + c];
    else if (k >= K_CAT_PAD) v = Wcont[(long)(k - K_CAT_PAD) * EMB + c];
    Bws[(long)c * K_PAD + k] = f2bf(v);
}

// Stage A: compress xcat (131 MB int32) -> bitmask [N][64 words] (4 MB).
// One wave per row-iteration: lane L loads ints {i*64+L}, ballot -> words 2i,2i+1;
// lane L ends holding word L; one coalesced 256B store per row.
__global__ __launch_bounds__(256, 8)
void compress_kernel(const int* __restrict__ xcat, uint32_t* __restrict__ bm) {
    const int wid  = (blockIdx.x * 256 + threadIdx.x) >> 6;  // global wave id, 0..4095
    const int lane = threadIdx.x & 63;
    #pragma unroll 1
    for (int rr = 0; rr < 4; ++rr) {
        const int row = wid * 4 + rr;
        const int* rp = xcat + (long)row * DCAT;
        uint32_t x[32];
        #pragma unroll
        for (int i = 0; i < 32; ++i) {
            const int idx = i * 64 + lane;
            x[i] = (idx < DCAT) ? (uint32_t)rp[idx] : 0u;
        }
        uint32_t w = 0;
        #pragma unroll
        for (int i = 0; i < 32; ++i) {
            unsigned long long b = __ballot(x[i] != 0u);
            w = (lane == 2 * i)     ? (uint32_t)b         : w;
            w = (lane == 2 * i + 1) ? (uint32_t)(b >> 32) : w;
        }
        bm[(long)row * 64 + lane] = w;
    }
}

struct BFrag { bf16x8 b0, b1, b2, b3; };       // 4 col-frags

__global__ __launch_bounds__(256, 4)
void fm_kernel(const float* __restrict__ xc,
               const uint32_t* __restrict__ bm,
               const uint16_t* __restrict__ Bws,
               float* __restrict__ out) {
    // 4 waves/block; each wave: SAME 32 rows, its own K-quarter (512 cat k = 16 words).
    // A-operand comes from the bitmask (64B/row), expanded in-register.
    __shared__ float part[4][BM][EMB];         // 32 KiB

    const int tid  = threadIdx.x;
    const int w    = tid >> 6;
    const int lane = tid & 63;
    const int g    = lane >> 4;
    const int lr   = lane & 15;
    const int r0   = blockIdx.x * BM;

    f32x4 acc[2][4] = { { {0,0,0,0},{0,0,0,0},{0,0,0,0},{0,0,0,0} },
                        { {0,0,0,0},{0,0,0,0},{0,0,0,0},{0,0,0,0} } };

    const int kw = w * 512;                    // this wave's cat k-range start
    const uint16_t* bP = Bws + (long)lr * K_PAD;

    // --- load this wave's bitmask slice: 16 words per row, 2 rows
    const uint32_t* bmP0 = bm + (long)(r0 + lr) * 64 + w * 16;
    const uint32_t* bmP1 = bm + (long)(r0 + 16 + lr) * 64 + w * 16;
    int4 m0[4], m1[4];
    #pragma unroll
    for (int q = 0; q < 4; ++q) {
        m0[q] = *(const int4*)(bmP0 + q * 4);
        m1[q] = *(const int4*)(bmP1 + q * 4);
    }

    auto loadB = [&](int kbase) -> BFrag {
        BFrag f;
        const int kg = kbase + g * 8;
        f.b0 = *(const bf16x8*)(bP + 0 * 16 * K_PAD + kg);
        f.b1 = *(const bf16x8*)(bP + 1 * 16 * K_PAD + kg);
        f.b2 = *(const bf16x8*)(bP + 2 * 16 * K_PAD + kg);
        f.b3 = *(const bf16x8*)(bP + 3 * 16 * K_PAD + kg);
        return f;
    };
    // expand 8 bits (byte g of word) -> 8 bf16 {0,1}
    auto expand = [&](uint32_t word) -> bf16x8 {
        const uint32_t b = (word >> (g * 8)) & 0xFFu;
        union { uint32_t u[4]; bf16x8 v; } cv;
        #pragma unroll
        for (int j = 0; j < 4; ++j) {
            const uint32_t b0 = (b >> (2 * j)) & 1u;
            const uint32_t b1 = (b >> (2 * j + 1)) & 1u;
            cv.u[j] = (b0 + (b1 << 16)) * 0x3F80u;
        }
        return cv.v;
    };
    auto mmac = [&](bf16x8 af0, bf16x8 af1, const BFrag& B) {
        acc[0][0] = __builtin_amdgcn_mfma_f32_16x16x32_bf16(af0, B.b0, acc[0][0], 0, 0, 0);
        acc[0][1] = __builtin_amdgcn_mfma_f32_16x16x32_bf16(af0, B.b1, acc[0][1], 0, 0, 0);
        acc[0][2] = __builtin_amdgcn_mfma_f32_16x16x32_bf16(af0, B.b2, acc[0][2], 0, 0, 0);
        acc[0][3] = __builtin_amdgcn_mfma_f32_16x16x32_bf16(af0, B.b3, acc[0][3], 0, 0, 0);
        acc[1][0] = __builtin_amdgcn_mfma_f32_16x16x32_bf16(af1, B.b0, acc[1][0], 0, 0, 0);
        acc[1][1] = __builtin_amdgcn_mfma_f32_16x16x32_bf16(af1, B.b1, acc[1][1], 0, 0, 0);
        acc[1][2] = __builtin_amdgcn_mfma_f32_16x16x32_bf16(af1, B.b2, acc[1][2], 0, 0, 0);
        acc[1][3] = __builtin_amdgcn_mfma_f32_16x16x32_bf16(af1, B.b3, acc[1][3], 0, 0, 0);
    };

    // --- main loop: 16 K-steps of 32; B 2-deep register pipeline; no barriers
    BFrag bb0 = loadB(kw), bb1 = loadB(kw + 32);
    #pragma unroll
    for (int s = 0; s < 16; ++s) {
        const int q = s >> 2, r = s & 3;
        uint32_t w0, w1;
        // static component select (fully unrolled, no scratch)
        w0 = (r == 0) ? m0[q].x : (r == 1) ? m0[q].y : (r == 2) ? m0[q].z : m0[q].w;
        w1 = (r == 0) ? m1[q].x : (r == 1) ? m1[q].y : (r == 2) ? m1[q].z : m1[q].w;
        bf16x8 af0 = expand(w0);
        bf16x8 af1 = expand(w1);
        __builtin_amdgcn_sched_barrier(0);
        if (s & 1) { mmac(af0, af1, bb1); if (s + 2 < 16) bb1 = loadB(kw + (s + 2) * 32); }
        else       { mmac(af0, af1, bb0); if (s + 2 < 16) bb0 = loadB(kw + (s + 2) * 32); }
        __builtin_amdgcn_sched_barrier(0);
    }

    // --- continuous part: waves 2,3 take one 32-wide K-step each
    if (w >= 2) {
        const int cs = w - 2;
        const float* xP0 = xc + (long)(r0 + lr) * DCONT + cs * 32 + g * 8;
        const float* xP1 = xc + (long)(r0 + 16 + lr) * DCONT + cs * 32 + g * 8;
        float4 x0 = *(const float4*)(xP0);
        float4 x1 = *(const float4*)(xP0 + 4);
        float4 x2 = *(const float4*)(xP1);
        float4 x3 = *(const float4*)(xP1 + 4);
        BFrag bc = loadB(K_CAT_PAD + cs * 32);
        union { uint32_t u[4]; bf16x8 v; } c0, c1;
        c0.u[0] = pack2f(x0.x, x0.y); c0.u[1] = pack2f(x0.z, x0.w);
        c0.u[2] = pack2f(x1.x, x1.y); c0.u[3] = pack2f(x1.z, x1.w);
        c1.u[0] = pack2f(x2.x, x2.y); c1.u[1] = pack2f(x2.z, x2.w);
        c1.u[2] = pack2f(x3.x, x3.y); c1.u[3] = pack2f(x3.z, x3.w);
        mmac(c0.v, c1.v, bc);
    }

    // --- epilogue: combine 4 wave-partials; out[r] = 0.5*||s_row||^2
    // lane (g,lr): rows rf*16 + g*4 + r, col n*16 + lr
    #pragma unroll
    for (int rf = 0; rf < 2; ++rf)
        #pragma unroll
        for (int n = 0; n < 4; ++n)
            #pragma unroll
            for (int r = 0; r < 4; ++r)
                part[w][rf * 16 + g * 4 + r][n * 16 + lr] = acc[rf][n][r];
    __syncthreads();

    const int row = tid >> 3;           // 0..31
    const int c0i = (tid & 7) * 8;      // 8 cols per thread
    float p = 0.f;
    #pragma unroll
    for (int h = 0; h < 2; ++h) {
        float4 v0 = *(const float4*)&part[0][row][c0i + h * 4];
        float4 v1 = *(const float4*)&part[1][row][c0i + h * 4];
        float4 v2 = *(const float4*)&part[2][row][c0i + h * 4];
        float4 v3 = *(const float4*)&part[3][row][c0i + h * 4];
        float sx = v0.x + v1.x + v2.x + v3.x;
        float sy = v0.y + v1.y + v2.y + v3.y;
        float sz = v0.z + v1.z + v2.z + v3.z;
        float sw_ = v0.w + v1.w + v2.w + v3.w;
        p += sx * sx + sy * sy + sz * sz + sw_ * sw_;
    }
    p += __shfl_xor(p, 1);
    p += __shfl_xor(p, 2);
    p += __shfl_xor(p, 4);
    if ((tid & 7) == 0) out[r0 + row] = 0.5f * p;
}

extern "C" void kernel_launch(void* const* d_in, const int* in_sizes, int n_in,
                              void* d_out, int out_size, void* d_ws, size_t ws_size,
                              hipStream_t stream) {
    const float* xc    = (const float*)d_in[0];   // data_continuous [N,64] f32
    const int*   xcat  = (const int*)d_in[1];     // data_category   [N,2000] i32
    const float* Wcont = (const float*)d_in[2];   // [64,64] f32
    const float* Wcat  = (const float*)d_in[3];   // [2000,64] f32
    uint16_t* Bws = (uint16_t*)d_ws;              // B_T[64][2112] bf16 = 264 KiB
    uint32_t* bm  = (uint32_t*)((char*)d_ws + BM_OFF);  // bitmask [N][64] = 4 MiB
    float* outp = (float*)d_out;

    build_b_kernel<<<dim3(K_PAD / 64, EMB), 64, 0, stream>>>(Wcont, Wcat, Bws);
    compress_kernel<<<1024, 256, 0, stream>>>(xcat, bm);
    fm_kernel<<<N_SAMP / BM, 256, 0, stream>>>(xc, bm, Bws, outp);
}